// Round 5
// baseline (309.946 us; speedup 1.0000x reference)
//
#include <hip/hip_runtime.h>
#include <cstdint>
#include <cstddef>

// ---------------------------------------------------------------------------
// MS-Deformable Attention forward, MI355X / gfx950 — round 5.
//  * GEMMs: 2-phase software pipeline (dbuf LDS, 1 barrier/K-step, loads for
//    t+1 issued before MFMA of t), XOR-swizzled frag-major LDS (conflict-free
//    write AND read), operand-swapped MFMA -> contiguous epilogue stores.
//  * Weights converted f32->f16 inside the GEMM staging (cvt_weights gone).
//  * Sampler: thread = (q, h, level): addr math /4, taps combined with
//    v_perm + v_dot2_f32_f16 (fp16 mul, fp32 acc), shuffle reduce-scatter.
// Launches: vproj, qproj, sampler, outproj (4 total).
// ---------------------------------------------------------------------------

#define L2_LEN 21760
#define BQ_TOT 16384

typedef __attribute__((ext_vector_type(8))) _Float16 half8;
typedef __attribute__((ext_vector_type(4))) _Float16 half4;
typedef __attribute__((ext_vector_type(2))) _Float16 half2v;
typedef __attribute__((ext_vector_type(4))) float    f32x4;

__device__ __forceinline__ void glds16(const _Float16* g, _Float16* l) {
    __builtin_amdgcn_global_load_lds(
        (const __attribute__((address_space(1))) void*)g,
        (__attribute__((address_space(3))) void*)l, 16, 0, 0);
}
__device__ __forceinline__ half8 cvt8(float4 a, float4 b) {
    half8 h;
    h[0] = (_Float16)a.x; h[1] = (_Float16)a.y;
    h[2] = (_Float16)a.z; h[3] = (_Float16)a.w;
    h[4] = (_Float16)b.x; h[5] = (_Float16)b.y;
    h[6] = (_Float16)b.z; h[7] = (_Float16)b.w;
    return h;
}
// frag-major chunk index with XOR bank swizzle. chunk c in [0,512):
// row=c>>2, kgrp=c&3; frag=row>>4; slot = frag*64 + ((kgrp*16 + row&15) ^ kgrp<<2)
__device__ __forceinline__ int swz_chunk(int c) {
    const int frag = c >> 6, r = (c >> 2) & 15, k = c & 3;
    return (frag * 64 + ((k * 16 + r) ^ (k << 2))) * 8;   // half offset
}

// ---------------------------------------------------------------------------
// vproj: vh[(b,h,l2,32)] fp16 = (value @ Wv^T + bv) * !mask.
// 256 thr = 4 waves (2x2), tile 128x128, K=256, BK=32, dbuf, 1 barrier/iter.
// ---------------------------------------------------------------------------
__global__ __launch_bounds__(256, 3) void gemm_vproj(
    const float* __restrict__ A, const float* __restrict__ Wv,
    const float* __restrict__ bv, const unsigned char* __restrict__ mask,
    _Float16* __restrict__ vh)
{
    __shared__ _Float16 As[2][4096];
    __shared__ _Float16 Bs[2][4096];

    const int t = threadIdx.x, lane = t & 63, wid = t >> 6;
    const int wm = wid >> 1, wn = wid & 1;
    const int bm = blockIdx.x, bn = blockIdx.y;

    const int r0 = t >> 2, kg = (t & 3) * 8;
    const float* Ag0 = A  + ((size_t)(bm * 128) + r0) * 256 + kg;
    const float* Ag1 = Ag0 + (size_t)64 * 256;
    const float* Bg0 = Wv + ((size_t)(bn * 128) + r0) * 256 + kg;
    const float* Bg1 = Bg0 + (size_t)64 * 256;
    const int d0 = swz_chunk(t), d1 = swz_chunk(t + 256);
    const int rsw = (lane ^ ((lane >> 4) << 2)) * 8;   // frag-read half offset

    f32x4 acc[4][4] = {};
    float4 pa0, pa1, pa2, pa3, pb0, pb1, pb2, pb3;

    // prologue: stage tile 0
    pa0 = *(const float4*)Ag0; pa1 = *(const float4*)(Ag0 + 4);
    pa2 = *(const float4*)Ag1; pa3 = *(const float4*)(Ag1 + 4);
    pb0 = *(const float4*)Bg0; pb1 = *(const float4*)(Bg0 + 4);
    pb2 = *(const float4*)Bg1; pb3 = *(const float4*)(Bg1 + 4);
    *(half8*)&As[0][d0] = cvt8(pa0, pa1); *(half8*)&As[0][d1] = cvt8(pa2, pa3);
    *(half8*)&Bs[0][d0] = cvt8(pb0, pb1); *(half8*)&Bs[0][d1] = cvt8(pb2, pb3);
    __syncthreads();

    for (int it = 0; it < 8; ++it) {
        const int cur = it & 1;
        if (it < 7) {                       // issue loads for t+1 (cover = MFMA phase)
            const int kk = (it + 1) * 32;
            pa0 = *(const float4*)(Ag0 + kk); pa1 = *(const float4*)(Ag0 + kk + 4);
            pa2 = *(const float4*)(Ag1 + kk); pa3 = *(const float4*)(Ag1 + kk + 4);
            pb0 = *(const float4*)(Bg0 + kk); pb1 = *(const float4*)(Bg0 + kk + 4);
            pb2 = *(const float4*)(Bg1 + kk); pb3 = *(const float4*)(Bg1 + kk + 4);
        }
        half8 ah[4], bh[4];
#pragma unroll
        for (int x = 0; x < 4; ++x) {
            ah[x] = *(const half8*)&As[cur][(wm * 4 + x) * 512 + rsw];
            bh[x] = *(const half8*)&Bs[cur][(wn * 4 + x) * 512 + rsw];
        }
#pragma unroll
        for (int m = 0; m < 4; ++m)
#pragma unroll
            for (int n = 0; n < 4; ++n)      // swapped: lane&15 -> M row, regs -> N cols
                acc[m][n] = __builtin_amdgcn_mfma_f32_16x16x32_f16(
                    bh[n], ah[m], acc[m][n], 0, 0, 0);
        if (it < 7) {
            *(half8*)&As[cur ^ 1][d0] = cvt8(pa0, pa1);
            *(half8*)&As[cur ^ 1][d1] = cvt8(pa2, pa3);
            *(half8*)&Bs[cur ^ 1][d0] = cvt8(pb0, pb1);
            *(half8*)&Bs[cur ^ 1][d1] = cvt8(pb2, pb3);
        }
        __syncthreads();
    }

    // epilogue: row = bm*128 + wm*64 + m*16 + (lane&15); cols = bn*128+wn*64+n*16+rl+r
    const int cl = lane & 15, rl = (lane >> 4) * 4;
    const int b = bm / 170;
#pragma unroll
    for (int m = 0; m < 4; ++m) {
        const int row = bm * 128 + wm * 64 + m * 16 + cl;
        const float mz = mask[row] ? 0.0f : 1.0f;
        const int l2i = row - b * L2_LEN;
#pragma unroll
        for (int n = 0; n < 4; ++n) {
            const int col = bn * 128 + wn * 64 + n * 16 + rl;   // 4 consecutive ch
            const float4 bb = *(const float4*)(bv + col);
            const int h = col >> 5, c = col & 31;
            half4 o;
            o[0] = (_Float16)((acc[m][n][0] + bb.x) * mz);
            o[1] = (_Float16)((acc[m][n][1] + bb.y) * mz);
            o[2] = (_Float16)((acc[m][n][2] + bb.z) * mz);
            o[3] = (_Float16)((acc[m][n][3] + bb.w) * mz);
            *(half4*)(vh + ((size_t)(b * 8 + h) * L2_LEN + l2i) * 32 + c) = o;
        }
    }
}

// ---------------------------------------------------------------------------
// qproj / outproj: C f32 = A @ W^T + b. Same pipeline. A_F16: A fp16 via
// glds (linear frag-major); else A f32 reg-staged (XOR-swizzled).
// W selected per column-tile: cb < n_split ? W0 : W1 (fused Wo|Wa).
// ---------------------------------------------------------------------------
template<bool A_F16>
__global__ __launch_bounds__(256, 3) void gemm_qo(
    const void* __restrict__ Av,
    const float* __restrict__ W0, const float* __restrict__ W1,
    const float* __restrict__ b0, const float* __restrict__ b1, int n_split,
    float* __restrict__ C, int ldC)
{
    __shared__ _Float16 As[2][4096];
    __shared__ _Float16 Bs[2][4096];

    const int t = threadIdx.x, lane = t & 63, wid = t >> 6;
    const int wm = wid >> 1, wn = wid & 1;
    const int bm = blockIdx.x, bn = blockIdx.y;

    const int cb = bn * 128;
    const float* Wt; const float* bt;
    if (cb < n_split) { Wt = W0 + (size_t)cb * 256;             bt = b0 + cb; }
    else              { Wt = W1 + (size_t)(cb - n_split) * 256; bt = b1 + (cb - n_split); }

    // B staging (f32 reg-stage, swizzled)
    const int r0 = t >> 2, kg = (t & 3) * 8;
    const float* Bg0 = Wt + ((size_t)r0) * 256 + kg;
    const float* Bg1 = Bg0 + (size_t)64 * 256;
    const int d0 = swz_chunk(t), d1 = swz_chunk(t + 256);
    const int rsw = (lane ^ ((lane >> 4) << 2)) * 8;

    // A staging
    const float* Agf0 = nullptr; const float* Agf1 = nullptr;
    const _Float16* Agh0 = nullptr; const _Float16* Agh1 = nullptr;
    _Float16* AdH0 = nullptr; _Float16* AdH1 = nullptr;
    if (A_F16) {
        const int u0 = wid * 128 + lane, u1 = u0 + 64;
        const int ar0 = ((u0 >> 6) << 4) + (u0 & 15), ak0 = ((u0 >> 4) & 3) * 8;
        const int ar1 = ((u1 >> 6) << 4) + (u1 & 15), ak1 = ((u1 >> 4) & 3) * 8;
        Agh0 = (const _Float16*)Av + ((size_t)(bm * 128) + ar0) * 256 + ak0;
        Agh1 = (const _Float16*)Av + ((size_t)(bm * 128) + ar1) * 256 + ak1;
        AdH0 = (_Float16*)&As[0][0] + wid * 1024;          // buffer offset added in loop
        AdH1 = AdH0 + 512;
    } else {
        Agf0 = (const float*)Av + ((size_t)(bm * 128) + r0) * 256 + kg;
        Agf1 = Agf0 + (size_t)64 * 256;
    }

    f32x4 acc[4][4] = {};
    float4 pa0, pa1, pa2, pa3, pb0, pb1, pb2, pb3;

    // prologue
    pb0 = *(const float4*)Bg0; pb1 = *(const float4*)(Bg0 + 4);
    pb2 = *(const float4*)Bg1; pb3 = *(const float4*)(Bg1 + 4);
    if (A_F16) { glds16(Agh0, AdH0); glds16(Agh1, AdH1); }
    else {
        pa0 = *(const float4*)Agf0; pa1 = *(const float4*)(Agf0 + 4);
        pa2 = *(const float4*)Agf1; pa3 = *(const float4*)(Agf1 + 4);
        *(half8*)&As[0][d0] = cvt8(pa0, pa1);
        *(half8*)&As[0][d1] = cvt8(pa2, pa3);
    }
    *(half8*)&Bs[0][d0] = cvt8(pb0, pb1);
    *(half8*)&Bs[0][d1] = cvt8(pb2, pb3);
    __syncthreads();

    for (int it = 0; it < 8; ++it) {
        const int cur = it & 1;
        if (it < 7) {
            const int kk = (it + 1) * 32;
            if (A_F16) {
                glds16(Agh0 + kk, AdH0 + (cur ^ 1) * 4096);
                glds16(Agh1 + kk, AdH1 + (cur ^ 1) * 4096);
            } else {
                pa0 = *(const float4*)(Agf0 + kk); pa1 = *(const float4*)(Agf0 + kk + 4);
                pa2 = *(const float4*)(Agf1 + kk); pa3 = *(const float4*)(Agf1 + kk + 4);
            }
            pb0 = *(const float4*)(Bg0 + kk); pb1 = *(const float4*)(Bg0 + kk + 4);
            pb2 = *(const float4*)(Bg1 + kk); pb3 = *(const float4*)(Bg1 + kk + 4);
        }
        half8 ah[4], bh[4];
#pragma unroll
        for (int x = 0; x < 4; ++x) {
            // glds path stored linear; reg path swizzled
            ah[x] = *(const half8*)&As[cur][(wm * 4 + x) * 512 + (A_F16 ? lane * 8 : rsw)];
            bh[x] = *(const half8*)&Bs[cur][(wn * 4 + x) * 512 + rsw];
        }
#pragma unroll
        for (int m = 0; m < 4; ++m)
#pragma unroll
            for (int n = 0; n < 4; ++n)
                acc[m][n] = __builtin_amdgcn_mfma_f32_16x16x32_f16(
                    bh[n], ah[m], acc[m][n], 0, 0, 0);
        if (it < 7) {
            if (!A_F16) {
                *(half8*)&As[cur ^ 1][d0] = cvt8(pa0, pa1);
                *(half8*)&As[cur ^ 1][d1] = cvt8(pa2, pa3);
            }
            *(half8*)&Bs[cur ^ 1][d0] = cvt8(pb0, pb1);
            *(half8*)&Bs[cur ^ 1][d1] = cvt8(pb2, pb3);
        }
        __syncthreads();
    }

    const int cl = lane & 15, rl = (lane >> 4) * 4;
#pragma unroll
    for (int m = 0; m < 4; ++m) {
        const int row = bm * 128 + wm * 64 + m * 16 + cl;
#pragma unroll
        for (int n = 0; n < 4; ++n) {
            const int co = wn * 64 + n * 16 + rl;
            const float4 bb = *(const float4*)(bt + co);
            float4 r;
            r.x = acc[m][n][0] + bb.x; r.y = acc[m][n][1] + bb.y;
            r.z = acc[m][n][2] + bb.z; r.w = acc[m][n][3] + bb.w;
            *(float4*)(C + (size_t)row * ldC + cb + co) = r;
        }
    }
}

// ---------------------------------------------------------------------------
// Sampler + fused softmax. 128 thr = 4 q x 8 h x 4 LEVELS. Each thread: its
// level's 4 points, all 32 ch. Taps combined via v_perm + v_dot2_f32_f16
// (fp16 mul, fp32 acc). 2-step shuffle reduce-scatter -> each lane stores an
// 8-ch quarter.
// ---------------------------------------------------------------------------
__global__ __launch_bounds__(128) void sample_fused(
    const _Float16* __restrict__ v,    // (4,8,21760,32) fp16
    const float* __restrict__ qp,      // (BQ,384): off(256) | logits(128)
    const float* __restrict__ ref,     // (BQ,4)
    const float* __restrict__ vrp,     // (4,4,2)
    float* __restrict__ attn_out,      // (BQ,8,16) f32
    _Float16* __restrict__ sout)       // (BQ,256) fp16
{
    const int t  = threadIdx.x;
    const int q  = blockIdx.x * 4 + (t >> 5);
    const int h  = (t >> 2) & 7;
    const int lv = t & 3;
    const int b  = q >> 12;

    // softmax (replicated across the 4 level-threads of a (q,h))
    const float* lg = qp + (size_t)q * 384 + 256 + h * 16;
    const float4 l0 = ((const float4*)lg)[0], l1 = ((const float4*)lg)[1];
    const float4 l2 = ((const float4*)lg)[2], l3 = ((const float4*)lg)[3];
    float e[16] = {l0.x, l0.y, l0.z, l0.w, l1.x, l1.y, l1.z, l1.w,
                   l2.x, l2.y, l2.z, l2.w, l3.x, l3.y, l3.z, l3.w};
    float mx = e[0];
#pragma unroll
    for (int j = 1; j < 16; ++j) mx = fmaxf(mx, e[j]);
    float sum = 0.0f;
#pragma unroll
    for (int j = 0; j < 16; ++j) { e[j] = __expf(e[j] - mx); sum += e[j]; }
    const float inv = 1.0f / sum;
    float aw[4];
#pragma unroll
    for (int p = 0; p < 4; ++p) aw[p] = e[lv * 4 + p] * inv;
    *(float4*)(attn_out + ((size_t)q * 8 + h) * 16 + lv * 4) =
        make_float4(aw[0], aw[1], aw[2], aw[3]);

    const float4 rw = *(const float4*)(ref + (size_t)q * 4);
    const float* op = qp + (size_t)q * 384 + h * 32 + lv * 8;
    const float4 o01 = ((const float4*)op)[0], o23 = ((const float4*)op)[1];
    const float oxv[4] = {o01.x, o01.z, o23.x, o23.z};
    const float oyv[4] = {o01.y, o01.w, o23.y, o23.w};

    const int HW = 128 >> lv;
    constexpr int SS[4] = {0, 16384, 20480, 21504};
    const int start = SS[0] * 0 + (lv == 0 ? 0 : (lv == 1 ? 16384 : (lv == 2 ? 20480 : 21504)));
    const float fHW = (float)HW;
    const float vrx = vrp[(b * 4 + lv) * 2 + 0];
    const float vry = vrp[(b * 4 + lv) * 2 + 1];
    const _Float16* vb = v + ((size_t)(b * 8 + h) * L2_LEN + start) * 32;

    float acc[32] = {};

#pragma unroll
    for (int p = 0; p < 4; ++p) {
        const float a = aw[p];
        const float x = (rw.x + oxv[p] * 0.125f * rw.z) * vrx * fHW - 0.5f;
        const float y = (rw.y + oyv[p] * 0.125f * rw.w) * vry * fHW - 0.5f;
        const float x0f = floorf(x), y0f = floorf(y);
        const float fx = x - x0f, fy = y - y0f;
        const int x0 = (int)x0f, y0 = (int)y0f;
        const float wx0 = (x0 >= 0 && x0 < HW)         ? (1.0f - fx) : 0.0f;
        const float wx1 = (x0 + 1 >= 0 && x0 + 1 < HW) ? fx          : 0.0f;
        const float wy0 = (y0 >= 0 && y0 < HW)         ? (1.0f - fy) : 0.0f;
        const float wy1 = (y0 + 1 >= 0 && y0 + 1 < HW) ? fy          : 0.0f;
        const int xc0 = min(max(x0, 0), HW - 1), xc1 = min(max(x0 + 1, 0), HW - 1);
        const int yc0 = min(max(y0, 0), HW - 1), yc1 = min(max(y0 + 1, 0), HW - 1);
        half2v wA, wB;
        wA[0] = (_Float16)(wx0 * wy0 * a); wA[1] = (_Float16)(wx1 * wy0 * a);
        wB[0] = (_Float16)(wx0 * wy1 * a); wB[1] = (_Float16)(wx1 * wy1 * a);

        const uint4* p00 = (const uint4*)(vb + (size_t)(yc0 * HW + xc0) * 32);
        const uint4* p01 = (const uint4*)(vb + (size_t)(yc0 * HW + xc1) * 32);
        const uint4* p10 = (const uint4*)(vb + (size_t)(yc1 * HW + xc0) * 32);
        const uint4* p11 = (const uint4*)(vb + (size_t)(yc1 * HW + xc1) * 32);
        unsigned u00[16], u01[16], u10[16], u11[16];
#pragma unroll
        for (int i = 0; i < 4; ++i) {
            *(uint4*)&u00[i * 4] = p00[i];
            *(uint4*)&u01[i * 4] = p01[i];
            *(uint4*)&u10[i * 4] = p10[i];
            *(uint4*)&u11[i * 4] = p11[i];
        }
#pragma unroll
        for (int d = 0; d < 16; ++d) {
            const unsigned loA = __builtin_amdgcn_perm(u00[d], u01[d], 0x01000504u);
            const unsigned hiA = __builtin_amdgcn_perm(u00[d], u01[d], 0x03020706u);
            const unsigned loB = __builtin_amdgcn_perm(u10[d], u11[d], 0x01000504u);
            const unsigned hiB = __builtin_amdgcn_perm(u10[d], u11[d], 0x03020706u);
#if __has_builtin(__builtin_amdgcn_fdot2)
            acc[2 * d]     = __builtin_amdgcn_fdot2(__builtin_bit_cast(half2v, loA), wA, acc[2 * d], false);
            acc[2 * d]     = __builtin_amdgcn_fdot2(__builtin_bit_cast(half2v, loB), wB, acc[2 * d], false);
            acc[2 * d + 1] = __builtin_amdgcn_fdot2(__builtin_bit_cast(half2v, hiA), wA, acc[2 * d + 1], false);
            acc[2 * d + 1] = __builtin_amdgcn_fdot2(__builtin_bit_cast(half2v, hiB), wB, acc[2 * d + 1], false);
#else
            const half2v xA = __builtin_bit_cast(half2v, loA), yA = __builtin_bit_cast(half2v, hiA);
            const half2v xB = __builtin_bit_cast(half2v, loB), yB = __builtin_bit_cast(half2v, hiB);
            acc[2 * d]     += (float)xA[0] * (float)wA[0] + (float)xA[1] * (float)wA[1]
                            + (float)xB[0] * (float)wB[0] + (float)xB[1] * (float)wB[1];
            acc[2 * d + 1] += (float)yA[0] * (float)wA[0] + (float)yA[1] * (float)wA[1]
                            + (float)yB[0] * (float)wB[0] + (float)yB[1] * (float)wB[1];
#endif
        }
    }

    // reduce-scatter across the 4 level-lanes (xor 1 then xor 2), static idx
    float t1[32];
#pragma unroll
    for (int j = 0; j < 32; ++j) t1[j] = __shfl_xor(acc[j], 1);
    float r16[16];
#pragma unroll
    for (int j = 0; j < 16; ++j)
        r16[j] = (lv & 1) ? (acc[16 + j] + t1[16 + j]) : (acc[j] + t1[j]);
    float t2[16];
#pragma unroll
    for (int j = 0; j < 16; ++j) t2[j] = __shfl_xor(r16[j], 2);
    float r8[8];
#pragma unroll
    for (int j = 0; j < 8; ++j)
        r8[j] = (lv & 2) ? (r16[8 + j] + t2[8 + j]) : (r16[j] + t2[j]);

    const int cq = ((lv & 1) << 4) | ((lv & 2) << 2);   // 0,16,8,24
    half8 o;
#pragma unroll
    for (int j = 0; j < 8; ++j) o[j] = (_Float16)r8[j];
    *(half8*)(sout + (size_t)q * 256 + h * 32 + cq) = o;
}

// ---------------------------------------------------------------------------
extern "C" void kernel_launch(void* const* d_in, const int* in_sizes, int n_in,
                              void* d_out, int out_size, void* d_ws, size_t ws_size,
                              hipStream_t stream)
{
    const float*         query    = (const float*)d_in[0];
    const float*         value    = (const float*)d_in[1];
    const unsigned char* v_mask   = (const unsigned char*)d_in[3];
    const float*         v_ratios = (const float*)d_in[5];
    const float*         ref_w    = (const float*)d_in[6];
    const float*         Wo       = (const float*)d_in[7];
    const float*         bo       = (const float*)d_in[8];
    const float*         Wa       = (const float*)d_in[9];
    const float*         ba       = (const float*)d_in[10];
    const float*         Wv       = (const float*)d_in[11];
    const float*         bv       = (const float*)d_in[12];
    const float*         Wout     = (const float*)d_in[13];
    const float*         bout     = (const float*)d_in[14];

    float* out      = (float*)d_out;                       // (16384, 256)
    float* attn_out = out + (size_t)BQ_TOT * 256;          // (16384, 128)

    float*    qp = (float*)d_ws;                           // (16384,384) f32
    _Float16* vh = (_Float16*)(qp + (size_t)BQ_TOT * 384); // (4,8,21760,32) fp16
    _Float16* Sf = vh + (size_t)4 * L2_LEN * 256;          // (16384,256) fp16

    // 1) value projection -> head-major fp16 (+mask)
    gemm_vproj<<<dim3(680, 2), 256, 0, stream>>>(value, Wv, bv, v_mask, vh);
    // 2) fused offset+logits projection: N=384 = Wo(256)|Wa(128)
    gemm_qo<false><<<dim3(128, 3), 256, 0, stream>>>(
        query, Wo, Wa, bo, ba, 256, qp, 384);
    // 3) sampler (+fused softmax -> attn_out)
    sample_fused<<<4096, 128, 0, stream>>>(vh, qp, ref_w, v_ratios, attn_out, Sf);
    // 4) output projection
    gemm_qo<true><<<dim3(128, 2), 256, 0, stream>>>(
        Sf, Wout, Wout, bout, bout, 256, out, 256);
}

// Round 6
// 276.471 us; speedup vs baseline: 1.1211x; 1.1211x over previous
//
#include <hip/hip_runtime.h>
#include <cstdint>
#include <cstddef>

// ---------------------------------------------------------------------------
// MS-Deformable Attention forward, MI355X / gfx950 — round 6.
//  * sampler: BACK to c0-split mapping (round-4 coalescing) + preloaded
//    offsets/logits + per-level batch of 16 tap loads in flight +
//    v_perm/fdot2 consumption (fp16 mul, fp32 acc).
//  * vproj: single-pass BN=256 (value read ONCE), 512 thr, dbuf 2-phase
//    pipeline, swizzled frag-major LDS, swapped-operand MFMA epilogue.
//  * qproj/outproj: round-5 pipelined versions (unchanged).
// Launches: vproj, qproj, sampler, outproj (4 total).
// ---------------------------------------------------------------------------

#define L2_LEN 21760
#define BQ_TOT 16384

typedef __attribute__((ext_vector_type(8))) _Float16 half8;
typedef __attribute__((ext_vector_type(4))) _Float16 half4;
typedef __attribute__((ext_vector_type(2))) _Float16 half2v;
typedef __attribute__((ext_vector_type(4))) float    f32x4;

__device__ __forceinline__ void glds16(const _Float16* g, _Float16* l) {
    __builtin_amdgcn_global_load_lds(
        (const __attribute__((address_space(1))) void*)g,
        (__attribute__((address_space(3))) void*)l, 16, 0, 0);
}
__device__ __forceinline__ half8 cvt8(float4 a, float4 b) {
    half8 h;
    h[0] = (_Float16)a.x; h[1] = (_Float16)a.y;
    h[2] = (_Float16)a.z; h[3] = (_Float16)a.w;
    h[4] = (_Float16)b.x; h[5] = (_Float16)b.y;
    h[6] = (_Float16)b.z; h[7] = (_Float16)b.w;
    return h;
}
// frag-major chunk -> swizzled half-offset. chunk c: row=c>>2, kgrp=c&3,
// frag=row>>4; slot = frag*64 + ((kgrp*16 + row&15) ^ (kgrp<<2)).
__device__ __forceinline__ int swz_chunk(int c) {
    const int frag = c >> 6, r = (c >> 2) & 15, k = c & 3;
    return (frag * 64 + ((k * 16 + r) ^ (k << 2))) * 8;
}

// ---------------------------------------------------------------------------
// vproj: vh[(b,h,l2,32)] fp16 = (value @ Wv^T + bv) * !mask.
// Tile 128M x 256N (single pass over N -> value read once), K=256, BK=32.
// 512 thr = 8 waves (2M x 4N); dbuf, 1 barrier/K-step, prefetch before MFMA.
// ---------------------------------------------------------------------------
__global__ __launch_bounds__(512) void gemm_vproj(
    const float* __restrict__ A, const float* __restrict__ Wv,
    const float* __restrict__ bv, const unsigned char* __restrict__ mask,
    _Float16* __restrict__ vh)
{
    __shared__ _Float16 As[2][4096];   // 128x32
    __shared__ _Float16 Bs[2][8192];   // 256x32

    const int t = threadIdx.x, lane = t & 63, wid = t >> 6;
    const int wm = wid >> 2, wn = wid & 3;
    const int bm = blockIdx.x;

    // A staging: thread t <-> chunk t (row=t>>2, k-el (t&3)*8)
    const float* Ag = A + ((size_t)(bm * 128) + (t >> 2)) * 256 + (t & 3) * 8;
    const int da = swz_chunk(t);
    // B staging: chunks t and t+512 (rows 0..127 / 128..255)
    const float* Bg0 = Wv + ((size_t)(t >> 2)) * 256 + (t & 3) * 8;
    const float* Bg1 = Bg0 + (size_t)128 * 256;
    const int db0 = swz_chunk(t), db1 = swz_chunk(t + 512);
    const int rsw = (lane ^ ((lane >> 4) << 2)) * 8;

    f32x4 acc[4][4] = {};
    float4 pa0, pa1, pb0, pb1, pb2, pb3;

    pa0 = *(const float4*)Ag;  pa1 = *(const float4*)(Ag + 4);
    pb0 = *(const float4*)Bg0; pb1 = *(const float4*)(Bg0 + 4);
    pb2 = *(const float4*)Bg1; pb3 = *(const float4*)(Bg1 + 4);
    *(half8*)&As[0][da]  = cvt8(pa0, pa1);
    *(half8*)&Bs[0][db0] = cvt8(pb0, pb1);
    *(half8*)&Bs[0][db1] = cvt8(pb2, pb3);
    __syncthreads();

    for (int it = 0; it < 8; ++it) {
        const int cur = it & 1;
        if (it < 7) {
            const int kk = (it + 1) * 32;
            pa0 = *(const float4*)(Ag + kk);  pa1 = *(const float4*)(Ag + kk + 4);
            pb0 = *(const float4*)(Bg0 + kk); pb1 = *(const float4*)(Bg0 + kk + 4);
            pb2 = *(const float4*)(Bg1 + kk); pb3 = *(const float4*)(Bg1 + kk + 4);
        }
        half8 ah[4], bh[4];
#pragma unroll
        for (int x = 0; x < 4; ++x) {
            ah[x] = *(const half8*)&As[cur][(wm * 4 + x) * 512 + rsw];
            bh[x] = *(const half8*)&Bs[cur][(wn * 4 + x) * 512 + rsw];
        }
#pragma unroll
        for (int m = 0; m < 4; ++m)
#pragma unroll
            for (int n = 0; n < 4; ++n)   // swapped: lane&15 -> M row, regs -> N cols
                acc[m][n] = __builtin_amdgcn_mfma_f32_16x16x32_f16(
                    bh[n], ah[m], acc[m][n], 0, 0, 0);
        if (it < 7) {
            *(half8*)&As[cur ^ 1][da]  = cvt8(pa0, pa1);
            *(half8*)&Bs[cur ^ 1][db0] = cvt8(pb0, pb1);
            *(half8*)&Bs[cur ^ 1][db1] = cvt8(pb2, pb3);
        }
        __syncthreads();
    }

    const int cl = lane & 15, rl = (lane >> 4) * 4;
    const int b = bm / 170;
#pragma unroll
    for (int m = 0; m < 4; ++m) {
        const int row = bm * 128 + wm * 64 + m * 16 + cl;
        const float mz = mask[row] ? 0.0f : 1.0f;
        const int l2i = row - b * L2_LEN;
#pragma unroll
        for (int n = 0; n < 4; ++n) {
            const int col = wn * 64 + n * 16 + rl;          // 0..255, 4 consec
            const float4 bb = *(const float4*)(bv + col);
            const int h = col >> 5, c = col & 31;
            half4 o;
            o[0] = (_Float16)((acc[m][n][0] + bb.x) * mz);
            o[1] = (_Float16)((acc[m][n][1] + bb.y) * mz);
            o[2] = (_Float16)((acc[m][n][2] + bb.z) * mz);
            o[3] = (_Float16)((acc[m][n][3] + bb.w) * mz);
            *(half4*)(vh + ((size_t)(b * 8 + h) * L2_LEN + l2i) * 32 + c) = o;
        }
    }
}

// ---------------------------------------------------------------------------
// qproj / outproj: C f32 = A @ W^T + b. 128x128 tile, 256 thr, dbuf pipeline.
// A_F16: A fp16 via glds (linear frag-major); else f32 reg-staged (swizzled).
// ---------------------------------------------------------------------------
template<bool A_F16>
__global__ __launch_bounds__(256, 3) void gemm_qo(
    const void* __restrict__ Av,
    const float* __restrict__ W0, const float* __restrict__ W1,
    const float* __restrict__ b0, const float* __restrict__ b1, int n_split,
    float* __restrict__ C, int ldC)
{
    __shared__ _Float16 As[2][4096];
    __shared__ _Float16 Bs[2][4096];

    const int t = threadIdx.x, lane = t & 63, wid = t >> 6;
    const int wm = wid >> 1, wn = wid & 1;
    const int bm = blockIdx.x, bn = blockIdx.y;

    const int cb = bn * 128;
    const float* Wt; const float* bt;
    if (cb < n_split) { Wt = W0 + (size_t)cb * 256;             bt = b0 + cb; }
    else              { Wt = W1 + (size_t)(cb - n_split) * 256; bt = b1 + (cb - n_split); }

    const int r0 = t >> 2, kg = (t & 3) * 8;
    const float* Bg0 = Wt + ((size_t)r0) * 256 + kg;
    const float* Bg1 = Bg0 + (size_t)64 * 256;
    const int d0 = swz_chunk(t), d1 = swz_chunk(t + 256);
    const int rsw = (lane ^ ((lane >> 4) << 2)) * 8;

    const float* Agf0 = nullptr; const float* Agf1 = nullptr;
    const _Float16* Agh0 = nullptr; const _Float16* Agh1 = nullptr;
    _Float16* AdH0 = nullptr; _Float16* AdH1 = nullptr;
    if (A_F16) {
        const int u0 = wid * 128 + lane, u1 = u0 + 64;
        const int ar0 = ((u0 >> 6) << 4) + (u0 & 15), ak0 = ((u0 >> 4) & 3) * 8;
        const int ar1 = ((u1 >> 6) << 4) + (u1 & 15), ak1 = ((u1 >> 4) & 3) * 8;
        Agh0 = (const _Float16*)Av + ((size_t)(bm * 128) + ar0) * 256 + ak0;
        Agh1 = (const _Float16*)Av + ((size_t)(bm * 128) + ar1) * 256 + ak1;
        AdH0 = (_Float16*)&As[0][0] + wid * 1024;
        AdH1 = AdH0 + 512;
    } else {
        Agf0 = (const float*)Av + ((size_t)(bm * 128) + r0) * 256 + kg;
        Agf1 = Agf0 + (size_t)64 * 256;
    }

    f32x4 acc[4][4] = {};
    float4 pa0, pa1, pa2, pa3, pb0, pb1, pb2, pb3;

    pb0 = *(const float4*)Bg0; pb1 = *(const float4*)(Bg0 + 4);
    pb2 = *(const float4*)Bg1; pb3 = *(const float4*)(Bg1 + 4);
    if (A_F16) { glds16(Agh0, AdH0); glds16(Agh1, AdH1); }
    else {
        pa0 = *(const float4*)Agf0; pa1 = *(const float4*)(Agf0 + 4);
        pa2 = *(const float4*)Agf1; pa3 = *(const float4*)(Agf1 + 4);
        *(half8*)&As[0][d0] = cvt8(pa0, pa1);
        *(half8*)&As[0][d1] = cvt8(pa2, pa3);
    }
    *(half8*)&Bs[0][d0] = cvt8(pb0, pb1);
    *(half8*)&Bs[0][d1] = cvt8(pb2, pb3);
    __syncthreads();

    for (int it = 0; it < 8; ++it) {
        const int cur = it & 1;
        if (it < 7) {
            const int kk = (it + 1) * 32;
            if (A_F16) {
                glds16(Agh0 + kk, AdH0 + (cur ^ 1) * 4096);
                glds16(Agh1 + kk, AdH1 + (cur ^ 1) * 4096);
            } else {
                pa0 = *(const float4*)(Agf0 + kk); pa1 = *(const float4*)(Agf0 + kk + 4);
                pa2 = *(const float4*)(Agf1 + kk); pa3 = *(const float4*)(Agf1 + kk + 4);
            }
            pb0 = *(const float4*)(Bg0 + kk); pb1 = *(const float4*)(Bg0 + kk + 4);
            pb2 = *(const float4*)(Bg1 + kk); pb3 = *(const float4*)(Bg1 + kk + 4);
        }
        half8 ah[4], bh[4];
#pragma unroll
        for (int x = 0; x < 4; ++x) {
            ah[x] = *(const half8*)&As[cur][(wm * 4 + x) * 512 + (A_F16 ? lane * 8 : rsw)];
            bh[x] = *(const half8*)&Bs[cur][(wn * 4 + x) * 512 + rsw];
        }
#pragma unroll
        for (int m = 0; m < 4; ++m)
#pragma unroll
            for (int n = 0; n < 4; ++n)
                acc[m][n] = __builtin_amdgcn_mfma_f32_16x16x32_f16(
                    bh[n], ah[m], acc[m][n], 0, 0, 0);
        if (it < 7) {
            if (!A_F16) {
                *(half8*)&As[cur ^ 1][d0] = cvt8(pa0, pa1);
                *(half8*)&As[cur ^ 1][d1] = cvt8(pa2, pa3);
            }
            *(half8*)&Bs[cur ^ 1][d0] = cvt8(pb0, pb1);
            *(half8*)&Bs[cur ^ 1][d1] = cvt8(pb2, pb3);
        }
        __syncthreads();
    }

    const int cl = lane & 15, rl = (lane >> 4) * 4;
#pragma unroll
    for (int m = 0; m < 4; ++m) {
        const int row = bm * 128 + wm * 64 + m * 16 + cl;
#pragma unroll
        for (int n = 0; n < 4; ++n) {
            const int co = wn * 64 + n * 16 + rl;
            const float4 bb = *(const float4*)(bt + co);
            float4 r;
            r.x = acc[m][n][0] + bb.x; r.y = acc[m][n][1] + bb.y;
            r.z = acc[m][n][2] + bb.z; r.w = acc[m][n][3] + bb.w;
            *(float4*)(C + (size_t)row * ldC + cb + co) = r;
        }
    }
}

// ---------------------------------------------------------------------------
// Sampler + fused softmax. 128 thr = 4 q x 8 h x 4 ch-groups(8) — coalesced:
// the 4 lanes of a (q,h) split each 64 B tap. Offsets/logits preloaded; per
// LEVEL all 16 tap loads (4 pts x 4 taps x 16 B) issued before consumption;
// taps combined via v_perm + fdot2 (fp16 mul, fp32 acc).
// ---------------------------------------------------------------------------
__global__ __launch_bounds__(128) void sample_fused(
    const _Float16* __restrict__ v,    // (4,8,21760,32) fp16
    const float* __restrict__ qp,      // (BQ,384): off(256) | logits(128)
    const float* __restrict__ ref,     // (BQ,4)
    const float* __restrict__ vrp,     // (4,4,2)
    float* __restrict__ attn_out,      // (BQ,8,16) f32
    _Float16* __restrict__ sout)       // (BQ,256) fp16
{
    const int t  = threadIdx.x;
    const int q  = blockIdx.x * 4 + (t >> 5);
    const int h  = (t >> 2) & 7;
    const int c0 = (t & 3) * 8;
    const int b  = q >> 12;

    // softmax over this (q,h)'s 16 logits (replicated across the 4 c0-lanes)
    const float* lg = qp + (size_t)q * 384 + 256 + h * 16;
    const float4 l0 = ((const float4*)lg)[0], l1 = ((const float4*)lg)[1];
    const float4 l2 = ((const float4*)lg)[2], l3 = ((const float4*)lg)[3];
    float aw[16] = {l0.x, l0.y, l0.z, l0.w, l1.x, l1.y, l1.z, l1.w,
                    l2.x, l2.y, l2.z, l2.w, l3.x, l3.y, l3.z, l3.w};
    float mx = aw[0];
#pragma unroll
    for (int j = 1; j < 16; ++j) mx = fmaxf(mx, aw[j]);
    float sum = 0.0f;
#pragma unroll
    for (int j = 0; j < 16; ++j) { aw[j] = __expf(aw[j] - mx); sum += aw[j]; }
    const float inv = 1.0f / sum;
#pragma unroll
    for (int j = 0; j < 16; ++j) aw[j] *= inv;
    if (c0 == 0) {
        float4* ao = (float4*)(attn_out + ((size_t)q * 8 + h) * 16);
        ao[0] = make_float4(aw[0], aw[1], aw[2], aw[3]);
        ao[1] = make_float4(aw[4], aw[5], aw[6], aw[7]);
        ao[2] = make_float4(aw[8], aw[9], aw[10], aw[11]);
        ao[3] = make_float4(aw[12], aw[13], aw[14], aw[15]);
    }

    // preload ALL offsets (16 points x 2) and per-batch valid ratios
    const float* op = qp + (size_t)q * 384 + h * 32;
    float4 of[8];
#pragma unroll
    for (int i = 0; i < 8; ++i) of[i] = ((const float4*)op)[i];
    const float4 rw = *(const float4*)(ref + (size_t)q * 4);
    const float4 vr01 = ((const float4*)(vrp + b * 8))[0];  // l0.xy, l1.xy
    const float4 vr23 = ((const float4*)(vrp + b * 8))[1];  // l2.xy, l3.xy

    const _Float16* vbase = v + ((size_t)(b * 8 + h) * L2_LEN) * 32 + c0;
    constexpr int SS[4] = {0, 16384, 20480, 21504};

    float acc[8] = {};

#pragma unroll
    for (int l = 0; l < 4; ++l) {
        const int HW = 128 >> l;
        const float fHW = (float)HW;
        const float vrx = (l == 0) ? vr01.x : (l == 1) ? vr01.z : (l == 2) ? vr23.x : vr23.z;
        const float vry = (l == 0) ? vr01.y : (l == 1) ? vr01.w : (l == 2) ? vr23.y : vr23.w;
        const _Float16* vb = vbase + (size_t)SS[l] * 32;

        // phase 1: all 4 points' addresses + weights, issue all 16 loads
        uint4  g[16];
        half2v wA[4], wB[4];
#pragma unroll
        for (int p = 0; p < 4; ++p) {
            const int pt = l * 4 + p;
            const float4 o4 = of[pt >> 1];
            const float ox = (pt & 1) ? o4.z : o4.x;
            const float oy = (pt & 1) ? o4.w : o4.y;
            const float a  = aw[pt];
            const float x = (rw.x + ox * 0.125f * rw.z) * vrx * fHW - 0.5f;
            const float y = (rw.y + oy * 0.125f * rw.w) * vry * fHW - 0.5f;
            const float x0f = floorf(x), y0f = floorf(y);
            const float fx = x - x0f, fy = y - y0f;
            const int x0 = (int)x0f, y0 = (int)y0f;
            const float wx0 = (x0 >= 0 && x0 < HW)         ? (1.0f - fx) : 0.0f;
            const float wx1 = (x0 + 1 >= 0 && x0 + 1 < HW) ? fx          : 0.0f;
            const float wy0 = (y0 >= 0 && y0 < HW)         ? (1.0f - fy) : 0.0f;
            const float wy1 = (y0 + 1 >= 0 && y0 + 1 < HW) ? fy          : 0.0f;
            const int xc0 = min(max(x0, 0), HW - 1), xc1 = min(max(x0 + 1, 0), HW - 1);
            const int yc0 = min(max(y0, 0), HW - 1), yc1 = min(max(y0 + 1, 0), HW - 1);
            wA[p][0] = (_Float16)(wx0 * wy0 * a); wA[p][1] = (_Float16)(wx1 * wy0 * a);
            wB[p][0] = (_Float16)(wx0 * wy1 * a); wB[p][1] = (_Float16)(wx1 * wy1 * a);
            g[p * 4 + 0] = *(const uint4*)(vb + (size_t)(yc0 * HW + xc0) * 32);
            g[p * 4 + 1] = *(const uint4*)(vb + (size_t)(yc0 * HW + xc1) * 32);
            g[p * 4 + 2] = *(const uint4*)(vb + (size_t)(yc1 * HW + xc0) * 32);
            g[p * 4 + 3] = *(const uint4*)(vb + (size_t)(yc1 * HW + xc1) * 32);
        }
        // phase 2: consume (perm pairs taps horizontally, fdot2 accumulates)
#pragma unroll
        for (int p = 0; p < 4; ++p) {
            const uint4 t00 = g[p * 4 + 0], t01 = g[p * 4 + 1];
            const uint4 t10 = g[p * 4 + 2], t11 = g[p * 4 + 3];
#pragma unroll
            for (int d = 0; d < 4; ++d) {
                const unsigned a0 = (&t00.x)[d], a1 = (&t01.x)[d];
                const unsigned b0_ = (&t10.x)[d], b1_ = (&t11.x)[d];
                const unsigned loA = __builtin_amdgcn_perm(a0, a1, 0x01000504u);
                const unsigned hiA = __builtin_amdgcn_perm(a0, a1, 0x03020706u);
                const unsigned loB = __builtin_amdgcn_perm(b0_, b1_, 0x01000504u);
                const unsigned hiB = __builtin_amdgcn_perm(b0_, b1_, 0x03020706u);
                acc[2 * d]     = __builtin_amdgcn_fdot2(__builtin_bit_cast(half2v, loA), wA[p], acc[2 * d],     false);
                acc[2 * d]     = __builtin_amdgcn_fdot2(__builtin_bit_cast(half2v, loB), wB[p], acc[2 * d],     false);
                acc[2 * d + 1] = __builtin_amdgcn_fdot2(__builtin_bit_cast(half2v, hiA), wA[p], acc[2 * d + 1], false);
                acc[2 * d + 1] = __builtin_amdgcn_fdot2(__builtin_bit_cast(half2v, hiB), wB[p], acc[2 * d + 1], false);
            }
        }
    }

    half8 o;
#pragma unroll
    for (int j = 0; j < 8; ++j) o[j] = (_Float16)acc[j];
    *(half8*)(sout + (size_t)q * 256 + h * 32 + c0) = o;
}

// ---------------------------------------------------------------------------
extern "C" void kernel_launch(void* const* d_in, const int* in_sizes, int n_in,
                              void* d_out, int out_size, void* d_ws, size_t ws_size,
                              hipStream_t stream)
{
    const float*         query    = (const float*)d_in[0];
    const float*         value    = (const float*)d_in[1];
    const unsigned char* v_mask   = (const unsigned char*)d_in[3];
    const float*         v_ratios = (const float*)d_in[5];
    const float*         ref_w    = (const float*)d_in[6];
    const float*         Wo       = (const float*)d_in[7];
    const float*         bo       = (const float*)d_in[8];
    const float*         Wa       = (const float*)d_in[9];
    const float*         ba       = (const float*)d_in[10];
    const float*         Wv       = (const float*)d_in[11];
    const float*         bv       = (const float*)d_in[12];
    const float*         Wout     = (const float*)d_in[13];
    const float*         bout     = (const float*)d_in[14];

    float* out      = (float*)d_out;                       // (16384, 256)
    float* attn_out = out + (size_t)BQ_TOT * 256;          // (16384, 128)

    float*    qp = (float*)d_ws;                           // (16384,384) f32
    _Float16* vh = (_Float16*)(qp + (size_t)BQ_TOT * 384); // (4,8,21760,32) fp16
    _Float16* Sf = vh + (size_t)4 * L2_LEN * 256;          // (16384,256) fp16

    // 1) value projection -> head-major fp16 (+mask), value read once
    gemm_vproj<<<680, 512, 0, stream>>>(value, Wv, bv, v_mask, vh);
    // 2) fused offset+logits projection: N=384 = Wo(256)|Wa(128)
    gemm_qo<false><<<dim3(128, 3), 256, 0, stream>>>(
        query, Wo, Wa, bo, ba, 256, qp, 384);
    // 3) sampler (+fused softmax -> attn_out)
    sample_fused<<<4096, 128, 0, stream>>>(vh, qp, ref_w, v_ratios, attn_out, Sf);
    // 4) output projection
    gemm_qo<true><<<dim3(128, 2), 256, 0, stream>>>(
        Sf, Wout, Wout, bout, bout, 256, out, 256);
}